// Round 10
// baseline (235.315 us; speedup 1.0000x reference)
//
#include <hip/hip_runtime.h>

typedef __bf16 bf16x8 __attribute__((ext_vector_type(8)));
typedef float f32x4 __attribute__((ext_vector_type(4)));

#define GLDS(g, l) __builtin_amdgcn_global_load_lds(                              \
    (const __attribute__((address_space(1))) void*)(g),                            \
    (__attribute__((address_space(3))) void*)(l), 16, 0, 0)

__device__ __forceinline__ unsigned short f2bf(float f) {
  unsigned int u = __builtin_bit_cast(unsigned int, f);
  u = (u + 0x7fffu + ((u >> 16) & 1u)) >> 16;
  return (unsigned short)u;
}
__device__ __forceinline__ float bf2f(unsigned short h) {
  unsigned int u = ((unsigned int)h) << 16;
  return __builtin_bit_cast(float, u);
}

// ---------------- merged convert ----------------
__global__ __launch_bounds__(256) void cvt_all(
    const float* __restrict__ hs, const float* __restrict__ w0,
    const float* __restrict__ w1, const float* __restrict__ w2,
    const float* __restrict__ w3, unsigned short* __restrict__ hs_bf,
    unsigned short* __restrict__ wall_bf) {
  const int i = blockIdx.x * 256 + threadIdx.x;
  const float* src;
  unsigned short* dst;
  int off;
  if (i < 2097152) { src = hs; dst = hs_bf; off = i; }
  else {
    const int j = i - 2097152;
    const int y = j >> 20;
    src = (y == 0) ? w0 : (y == 1) ? w1 : (y == 2) ? w2 : w3;
    dst = wall_bf + (size_t)y * 4194304;
    off = j & 1048575;
  }
  float4 v = ((const float4*)src)[off];
  ushort4 o;
  o.x = f2bf(v.x); o.y = f2bf(v.y); o.z = f2bf(v.z); o.w = f2bf(v.w);
  ((ushort4*)dst)[off] = o;
}

// ============ QKV GEMM: 256x256, 8-phase half-recycled, COUNTED vmcnt(4) ============
// 8 waves 2M x 4N interleaved: per phase (mh,nh) ALL waves read only LDS half A-mh, B-nh.
// Wave rows = mh*128 + wm*64 + mq*16..; cols = nh*128 + wn*32 + nq*16.. (strip-interleaved).
// Stage 1 half/phase into the slot that just died; waits: vmcnt(4) at ph4/ph8 ends ONLY.
// LDS 128KB = 2buf x 2half x (A 16KB + B 16KB). Grid 16x24 = 384.
__global__ __launch_bounds__(512, 2) void gemm256_qkv(
    const unsigned short* __restrict__ A, const unsigned short* __restrict__ Bw,
    const float* __restrict__ bq, const float* __restrict__ bk, const float* __restrict__ bv,
    unsigned short* __restrict__ oQ, unsigned short* __restrict__ oK,
    unsigned short* __restrict__ oV) {
  constexpr int K = 2048;
  __shared__ unsigned short lds[65536];   // A slots (b*2+h)*8192 @0; B same @32768
  const int tid = threadIdx.x, lane = tid & 63, wid = tid >> 6;
  const int wm = wid >> 2;         // 0..1
  const int wn = wid & 3;          // 0..3
  const int l15 = lane & 15;

  const int g0 = blockIdx.x;
  const int wg = (g0 & 7) * 48 + (g0 >> 3);
  const int bx = wg / 16;          // 0..23 N-tiles
  const int by = wg % 16;          // 0..15 M-tiles

  const int srow = tid >> 3;
  const size_t gsw = (size_t)(((lane & 7) ^ (srow & 7)) << 3);
  const unsigned short* gA = A  + (size_t)(by * 256 + srow) * K + gsw;
  const unsigned short* gB = Bw + (size_t)(bx * 256 + srow) * K + gsw;

#define STAGE_A(b, h, tt)                                                                    \
  do {                                                                                       \
    GLDS(gA + (size_t)((h) * 128) * K + (size_t)(tt) * 64,                                   \
         lds + ((b) * 2 + (h)) * 8192 + wid * 512);                                          \
    GLDS(gA + (size_t)((h) * 128 + 64) * K + (size_t)(tt) * 64,                              \
         lds + ((b) * 2 + (h)) * 8192 + 4096 + wid * 512);                                   \
  } while (0)
#define STAGE_B(b, h, tt)                                                                    \
  do {                                                                                       \
    GLDS(gB + (size_t)((h) * 128) * K + (size_t)(tt) * 64,                                   \
         lds + 32768 + ((b) * 2 + (h)) * 8192 + wid * 512);                                  \
    GLDS(gB + (size_t)((h) * 128 + 64) * K + (size_t)(tt) * 64,                              \
         lds + 32768 + ((b) * 2 + (h)) * 8192 + 4096 + wid * 512);                           \
  } while (0)

  const int sw0 = (((lane >> 4)) ^ (lane & 7)) << 3;
  const int sw1 = ((4 + (lane >> 4)) ^ (lane & 7)) << 3;
  const int aro = (wm * 64 + l15) * 64;   // + mq*1024 + slot
  const int bro = (wn * 32 + l15) * 64;   // + nq*1024 + slot

  f32x4 acc[8][4] = {};
  bf16x8 Af[8], Bf[4];

#define PH_CORE(BUF, MH, NH, LA, LB)                                                         \
  do {                                                                                       \
    if (LA) {                                                                                \
      const int ab_ = ((BUF) * 2 + (MH)) * 8192 + aro;                                       \
      _Pragma("unroll") for (int mq = 0; mq < 4; ++mq) {                                     \
        Af[mq * 2]     = *(const bf16x8*)&lds[ab_ + mq * 1024 + sw0];                        \
        Af[mq * 2 + 1] = *(const bf16x8*)&lds[ab_ + mq * 1024 + sw1];                        \
      }                                                                                      \
    }                                                                                        \
    if (LB) {                                                                                \
      const int bb_ = 32768 + ((BUF) * 2 + (NH)) * 8192 + bro;                               \
      _Pragma("unroll") for (int nq = 0; nq < 2; ++nq) {                                     \
        Bf[nq * 2]     = *(const bf16x8*)&lds[bb_ + nq * 1024 + sw0];                        \
        Bf[nq * 2 + 1] = *(const bf16x8*)&lds[bb_ + nq * 1024 + sw1];                        \
      }                                                                                      \
    }                                                                                        \
    __builtin_amdgcn_sched_barrier(0);                                                       \
    __builtin_amdgcn_s_barrier();                                                            \
    asm volatile("s_waitcnt lgkmcnt(0)" ::: "memory");                                       \
    __builtin_amdgcn_sched_barrier(0);                                                       \
    __builtin_amdgcn_s_setprio(1);                                                           \
    _Pragma("unroll") for (int mq = 0; mq < 4; ++mq)                                         \
      _Pragma("unroll") for (int nq = 0; nq < 2; ++nq)                                       \
        _Pragma("unroll") for (int kk = 0; kk < 2; ++kk)                                     \
          acc[(MH) * 4 + mq][(NH) * 2 + nq] = __builtin_amdgcn_mfma_f32_16x16x32_bf16(       \
              Af[mq * 2 + kk], Bf[nq * 2 + kk], acc[(MH) * 4 + mq][(NH) * 2 + nq], 0, 0, 0); \
    __builtin_amdgcn_s_setprio(0);                                                           \
  } while (0)

  // prologue: tile0 (A0,A1,B0,B1) + B0(1), A1(1); wait first 8 -> vmcnt(4)
  STAGE_A(0, 0, 0); STAGE_A(0, 1, 0); STAGE_B(0, 0, 0); STAGE_B(0, 1, 0);
  STAGE_B(1, 0, 1); STAGE_A(1, 1, 1);
  asm volatile("s_waitcnt vmcnt(4)" ::: "memory");
  __builtin_amdgcn_s_barrier();

  for (int g = 0; g < 16; ++g) {
    const bool full = (g < 15);
    const int t0 = 2 * g;

    // ---- tile t0 (buf0) ----
    STAGE_B(1, 1, t0 + 1);                       // ph1: buf1.B1 dead since prev ph8
    PH_CORE(0, 0, 0, 1, 1);
    __builtin_amdgcn_s_barrier();

    STAGE_A(1, 0, t0 + 1);                       // ph2: buf1.A0 dead since prev ph8
    PH_CORE(0, 1, 0, 1, 0);
    __builtin_amdgcn_s_barrier();

    if (full) STAGE_B(0, 0, t0 + 2);             // ph3: buf0.B0 last read ph2
    PH_CORE(0, 1, 1, 0, 1);
    __builtin_amdgcn_s_barrier();

    if (full) STAGE_A(0, 1, t0 + 2);             // ph4: buf0.A1 last read ph3
    PH_CORE(0, 0, 1, 1, 0);
    if (full) asm volatile("s_waitcnt vmcnt(4)" ::: "memory");
    else      asm volatile("s_waitcnt vmcnt(0)" ::: "memory");
    __builtin_amdgcn_s_barrier();

    // ---- tile t0+1 (buf1) ----
    if (full) STAGE_B(0, 1, t0 + 2);             // ph5: buf0.B1 last read ph4
    PH_CORE(1, 0, 0, 1, 1);
    __builtin_amdgcn_s_barrier();

    if (full) STAGE_A(0, 0, t0 + 2);             // ph6: buf0.A0 last read ph4
    PH_CORE(1, 1, 0, 1, 0);
    __builtin_amdgcn_s_barrier();

    if (full) STAGE_B(1, 0, t0 + 3);             // ph7: buf1.B0 last read ph6
    PH_CORE(1, 1, 1, 0, 1);
    __builtin_amdgcn_s_barrier();

    if (full) STAGE_A(1, 1, t0 + 3);             // ph8: buf1.A1 last read ph7
    PH_CORE(1, 0, 1, 1, 0);
    if (full) asm volatile("s_waitcnt vmcnt(4)" ::: "memory");
    __builtin_amdgcn_s_barrier();
  }

  // ---------------- featmap epilogue with cross-wave strip-sum exchange ----------------
  float* tab = (float*)lds;                      // 8 strips x 64 rows = 2 KB
  const int rsub = (lane >> 4) << 2;
  const int hp = wn >> 1, strip = wn & 1;
#pragma unroll
  for (int nh = 0; nh < 2; ++nh) {
    const int headg = bx * 4 + nh * 2 + hp;      // 0..95, uniform per wave
    const int type = headg >> 5;
    const int h = headg & 31;
    const float* bias = (type == 0) ? bq : (type == 1) ? bk : bv;
    unsigned short* dst = (type == 0) ? oQ : (type == 1) ? oK : oV;
    float bv2[2];
#pragma unroll
    for (int nq = 0; nq < 2; ++nq) bv2[nq] = bias[h * 64 + strip * 32 + nq * 16 + l15];
#pragma unroll
    for (int mh = 0; mh < 2; ++mh) {
      float ev[4][2][4];
      float ss[4][4];
#pragma unroll
      for (int mq = 0; mq < 4; ++mq)
#pragma unroll
        for (int r = 0; r < 4; ++r) {
          float s_ = 0.f;
#pragma unroll
          for (int nq = 0; nq < 2; ++nq) {
            float v = acc[mh * 4 + mq][nh * 2 + nq][r] + bv2[nq];
            if (type == 0) v *= 0.125f;
            if (type < 2) v = (v > 0.f) ? (v + 1.f) : __expf(v);
            ev[mq][nq][r] = v; s_ += v;
          }
#pragma unroll
          for (int off = 1; off < 16; off <<= 1) s_ += __shfl_xor(s_, off, 64);
          ss[mq][r] = s_;
        }
      const int tbase = ((wm * 2 + hp) * 2 + strip) * 64;
      if (type < 2 && (lane & 15) == 0) {
#pragma unroll
        for (int mq = 0; mq < 4; ++mq)
#pragma unroll
          for (int r = 0; r < 4; ++r)
            tab[tbase + mq * 16 + rsub + r] = ss[mq][r];
      }
      __syncthreads();
      const int pbase = ((wm * 2 + hp) * 2 + (strip ^ 1)) * 64;
#pragma unroll
      for (int mq = 0; mq < 4; ++mq) {
#pragma unroll
        for (int r = 0; r < 4; ++r) {
          float inv = 1.f;
          if (type < 2) {
            const float tot = ss[mq][r] + tab[pbase + mq * 16 + rsub + r];
            inv = 1.f / (tot + 1e-4f);
          }
          const int row = by * 256 + mh * 128 + wm * 64 + mq * 16 + rsub + r;
          const int bb = row >> 11, sx = row & 2047;
          const size_t obase = ((size_t)((bb << 5) + h) * 2048 + sx) * 64 + strip * 32;
#pragma unroll
          for (int nq = 0; nq < 2; ++nq)
            dst[obase + nq * 16 + l15] = f2bf(ev[mq][nq][r] * inv);
        }
      }
      __syncthreads();
    }
  }
#undef STAGE_A
#undef STAGE_B
#undef PH_CORE
}

// ---------------- wo GEMM (proven): BM=128 BN=256 BK=64, 3-buf, grid 256 ----------------
__global__ __launch_bounds__(512, 2) void gemm128_wo(
    const unsigned short* __restrict__ A, const unsigned short* __restrict__ Bw,
    const float* __restrict__ b0, float* __restrict__ C) {
  constexpr int K = 2048, NT = 32;
  __shared__ unsigned short lds[73728];
  const int tid = threadIdx.x, lane = tid & 63, wid = tid >> 6;
  const int wm = wid >> 2, wn = wid & 3;

  const int g0 = blockIdx.x;
  const int wg = (g0 & 7) * 32 + (g0 >> 3);
  const int l = wg % 32;
  const int chunk = wg / 32;
  const int bx2 = (chunk % 4) * 2 + l / 16;
  const int by2 = (chunk / 4) * 16 + l % 16;

  const int rloc = wid * 8 + (lane >> 3);
  const size_t gcoff = (size_t)(((lane & 7) ^ (lane >> 3)) << 3);
  const unsigned short* gA[2];
  const unsigned short* gB[4];
#pragma unroll
  for (int c = 0; c < 2; ++c) gA[c] = A + (size_t)(by2 * 128 + c * 64 + rloc) * K + gcoff;
#pragma unroll
  for (int c = 0; c < 4; ++c) gB[c] = Bw + (size_t)(bx2 * 256 + c * 64 + rloc) * K + gcoff;

  int aoff[4][2], boff[4][2];
#pragma unroll
  for (int m = 0; m < 4; ++m)
#pragma unroll
    for (int kk = 0; kk < 2; ++kk) {
      aoff[m][kk] = (wm * 64 + m * 16 + (lane & 15)) * 64 +
                    ((((kk << 2) + (lane >> 4)) ^ (lane & 7)) << 3);
      boff[m][kk] = (wn * 64 + m * 16 + (lane & 15)) * 64 +
                    ((((kk << 2) + (lane >> 4)) ^ (lane & 7)) << 3);
    }

  f32x4 acc[4][4] = {};

#define AB(b) ((b) * 8192)
#define BB(b) (24576 + (b) * 16384)
#define STAGE_A(c, b) GLDS(gA[c], lds + AB(b) + (c) * 4096 + wid * 512)
#define STAGE_B(c, b) GLDS(gB[c], lds + BB(b) + (c) * 4096 + wid * 512)

  STAGE_A(0, 0); STAGE_A(1, 0); STAGE_B(0, 0); STAGE_B(1, 0); STAGE_B(2, 0); STAGE_B(3, 0);
#pragma unroll
  for (int c = 0; c < 2; ++c) gA[c] += 64;
#pragma unroll
  for (int c = 0; c < 4; ++c) gB[c] += 64;
  STAGE_A(0, 1); STAGE_A(1, 1); STAGE_B(0, 1); STAGE_B(1, 1); STAGE_B(2, 1); STAGE_B(3, 1);
#pragma unroll
  for (int c = 0; c < 2; ++c) gA[c] += 64;
#pragma unroll
  for (int c = 0; c < 4; ++c) gB[c] += 64;
  asm volatile("s_waitcnt vmcnt(6)" ::: "memory");
  __builtin_amdgcn_s_barrier();

  for (int t = 0; t < NT; ++t) {
    const int b = t % 3;
    const int sb = (t + 2) % 3;
    const bool doStage = (t + 2 < NT);

    if (doStage) { STAGE_A(0, sb); STAGE_A(1, sb); STAGE_B(0, sb); STAGE_B(1, sb); }
    bf16x8 af[4], bfr[4];
#pragma unroll
    for (int m = 0; m < 4; ++m) af[m] = *(const bf16x8*)&lds[AB(b) + aoff[m][0]];
#pragma unroll
    for (int n = 0; n < 4; ++n) bfr[n] = *(const bf16x8*)&lds[BB(b) + boff[n][0]];
    __builtin_amdgcn_s_barrier();
    __builtin_amdgcn_s_setprio(1);
#pragma unroll
    for (int m = 0; m < 4; ++m)
#pragma unroll
      for (int n = 0; n < 4; ++n)
        acc[m][n] = __builtin_amdgcn_mfma_f32_16x16x32_bf16(af[m], bfr[n], acc[m][n], 0, 0, 0);
    __builtin_amdgcn_s_setprio(0);
    __builtin_amdgcn_s_barrier();

    if (doStage) { STAGE_B(2, sb); STAGE_B(3, sb); }
#pragma unroll
    for (int c = 0; c < 2; ++c) gA[c] += 64;
#pragma unroll
    for (int c = 0; c < 4; ++c) gB[c] += 64;
#pragma unroll
    for (int m = 0; m < 4; ++m) af[m] = *(const bf16x8*)&lds[AB(b) + aoff[m][1]];
#pragma unroll
    for (int n = 0; n < 4; ++n) bfr[n] = *(const bf16x8*)&lds[BB(b) + boff[n][1]];
    __builtin_amdgcn_s_barrier();
    __builtin_amdgcn_s_setprio(1);
#pragma unroll
    for (int m = 0; m < 4; ++m)
#pragma unroll
      for (int n = 0; n < 4; ++n)
        acc[m][n] = __builtin_amdgcn_mfma_f32_16x16x32_bf16(af[m], bfr[n], acc[m][n], 0, 0, 0);
    __builtin_amdgcn_s_setprio(0);
    if (t < NT - 1) {
      if (doStage) asm volatile("s_waitcnt vmcnt(6)" ::: "memory");
      else         asm volatile("s_waitcnt vmcnt(0)" ::: "memory");
    }
    __builtin_amdgcn_s_barrier();
  }

#pragma unroll
  for (int n = 0; n < 4; ++n) {
    const int col = bx2 * 256 + wn * 64 + n * 16 + (lane & 15);
    const float bv_ = b0[col];
#pragma unroll
    for (int m = 0; m < 4; ++m) {
      const int row0 = by2 * 128 + wm * 64 + m * 16 + ((lane >> 4) << 2);
#pragma unroll
      for (int r = 0; r < 4; ++r)
        C[(size_t)(row0 + r) * 2048 + col] = acc[m][n][r] + bv_;
    }
  }
#undef AB
#undef BB
#undef STAGE_A
#undef STAGE_B
}

// ---------------- pass1: per-chunk stateT[d][e] = sum_t v[t,d]*k[t,e] ----------------
__global__ __launch_bounds__(256) void chunk_state(
    const unsigned short* __restrict__ Kn, const unsigned short* __restrict__ Vn,
    unsigned short* __restrict__ stT) {
  __shared__ unsigned short Kt[64 * 72];
  __shared__ unsigned short Vt[64 * 72];
  const int c = blockIdx.x, bh = blockIdx.y;
  const int tid = threadIdx.x, lane = tid & 63, wid = tid >> 6;
  const size_t base = (size_t)bh * 2048 * 64 + (size_t)c * 64 * 64;
#pragma unroll
  for (int i = 0; i < 16; ++i) {
    const int ii = i * 256 + tid;
    const int t = ii >> 6, d = ii & 63;
    Kt[d * 72 + t] = Kn[base + ii];
    Vt[d * 72 + t] = Vn[base + ii];
  }
  __syncthreads();
  f32x4 acc[4] = {};
#pragma unroll
  for (int ks = 0; ks < 2; ++ks) {
    const int ko = ks * 32 + (lane >> 4) * 8;
    bf16x8 a = *(const bf16x8*)&Vt[(wid * 16 + (lane & 15)) * 72 + ko];
#pragma unroll
    for (int ej = 0; ej < 4; ++ej) {
      bf16x8 bb = *(const bf16x8*)&Kt[(ej * 16 + (lane & 15)) * 72 + ko];
      acc[ej] = __builtin_amdgcn_mfma_f32_16x16x32_bf16(a, bb, acc[ej], 0, 0, 0);
    }
  }
  const size_t obase = ((size_t)bh * 32 + c) * 4096;
#pragma unroll
  for (int ej = 0; ej < 4; ++ej) {
    const int e = ej * 16 + (lane & 15);
    const int d0 = wid * 16 + ((lane >> 4) << 2);
#pragma unroll
    for (int r = 0; r < 4; ++r)
      stT[obase + (size_t)(d0 + r) * 64 + e] = f2bf(acc[ej][r]);
  }
}

// ---------------- pass2: exclusive prefix over chunks ----------------
__global__ __launch_bounds__(256) void prefix_state(
    const unsigned short* __restrict__ stT, unsigned short* __restrict__ cumT) {
  const int g = blockIdx.x * 256 + threadIdx.x;
  const int bh = g >> 12, e = g & 4095;
  float run = 0.f;
  for (int c = 0; c < 32; ++c) {
    const size_t idx = (((size_t)bh * 32 + c) << 12) + e;
    const float v = bf2f(stT[idx]);
    cumT[idx] = f2bf(run);
    run += v;
  }
}

// ---------------- pass3: out = (tril(Q K^T) V + Q stateT) * 0.125 ----------------
__global__ __launch_bounds__(256) void attn_intra(
    const unsigned short* __restrict__ Qn, const unsigned short* __restrict__ Kn,
    const unsigned short* __restrict__ Vn, const unsigned short* __restrict__ cumT,
    unsigned short* __restrict__ aout) {
  __shared__ unsigned short Qs[64 * 72];
  __shared__ unsigned short Ks[64 * 72];
  __shared__ unsigned short Vt[64 * 72];
  __shared__ unsigned short St[64 * 72];
  __shared__ unsigned short Ps[64 * 72];
  const int c = blockIdx.x, bh = blockIdx.y;
  const int tid = threadIdx.x, lane = tid & 63, wid = tid >> 6;
  const size_t base = (size_t)bh * 2048 * 64 + (size_t)c * 64 * 64;
  const size_t sbase = ((size_t)bh * 32 + c) * 4096;
#pragma unroll
  for (int i = 0; i < 16; ++i) {
    const int ii = i * 256 + tid;
    const int t = ii >> 6, d = ii & 63;
    Qs[t * 72 + d] = Qn[base + ii];
    Ks[t * 72 + d] = Kn[base + ii];
    Vt[d * 72 + t] = Vn[base + ii];
    St[t * 72 + d] = cumT[sbase + ii];
  }
  __syncthreads();
  f32x4 sacc[4] = {};
#pragma unroll
  for (int ks = 0; ks < 2; ++ks) {
    const int ko = ks * 32 + (lane >> 4) * 8;
    bf16x8 a = *(const bf16x8*)&Qs[(wid * 16 + (lane & 15)) * 72 + ko];
#pragma unroll
    for (int tj = 0; tj < 4; ++tj) {
      bf16x8 bb = *(const bf16x8*)&Ks[(tj * 16 + (lane & 15)) * 72 + ko];
      sacc[tj] = __builtin_amdgcn_mfma_f32_16x16x32_bf16(a, bb, sacc[tj], 0, 0, 0);
    }
  }
#pragma unroll
  for (int tj = 0; tj < 4; ++tj) {
    const int t = tj * 16 + (lane & 15);
    const int s0 = wid * 16 + ((lane >> 4) << 2);
#pragma unroll
    for (int r = 0; r < 4; ++r) {
      const float v = (t <= s0 + r) ? sacc[tj][r] : 0.f;
      Ps[(s0 + r) * 72 + t] = f2bf(v);
    }
  }
  __syncthreads();
  f32x4 oacc[4] = {};
#pragma unroll
  for (int ks = 0; ks < 2; ++ks) {
    const int ko = ks * 32 + (lane >> 4) * 8;
    bf16x8 a = *(const bf16x8*)&Ps[(wid * 16 + (lane & 15)) * 72 + ko];
    bf16x8 a2 = *(const bf16x8*)&Qs[(wid * 16 + (lane & 15)) * 72 + ko];
#pragma unroll
    for (int dj = 0; dj < 4; ++dj) {
      bf16x8 bv_ = *(const bf16x8*)&Vt[(dj * 16 + (lane & 15)) * 72 + ko];
      oacc[dj] = __builtin_amdgcn_mfma_f32_16x16x32_bf16(a, bv_, oacc[dj], 0, 0, 0);
      bf16x8 bs_ = *(const bf16x8*)&St[(dj * 16 + (lane & 15)) * 72 + ko];
      oacc[dj] = __builtin_amdgcn_mfma_f32_16x16x32_bf16(a2, bs_, oacc[dj], 0, 0, 0);
    }
  }
  const int b = bh >> 5, h = bh & 31;
#pragma unroll
  for (int dj = 0; dj < 4; ++dj) {
    const int d = dj * 16 + (lane & 15);
    const int s0 = wid * 16 + ((lane >> 4) << 2);
#pragma unroll
    for (int r = 0; r < 4; ++r) {
      const size_t row = (size_t)(b * 2048 + c * 64 + s0 + r);
      aout[row * 2048 + h * 64 + d] = f2bf(0.125f * oacc[dj][r]);
    }
  }
}

extern "C" void kernel_launch(void* const* d_in, const int* in_sizes, int n_in,
                              void* d_out, int out_size, void* d_ws, size_t ws_size,
                              hipStream_t stream) {
  const float* hs = (const float*)d_in[0];
  const float* wq = (const float*)d_in[2];
  const float* bq = (const float*)d_in[3];
  const float* wk = (const float*)d_in[4];
  const float* bk = (const float*)d_in[5];
  const float* wv = (const float*)d_in[6];
  const float* bv = (const float*)d_in[7];
  const float* wo = (const float*)d_in[8];
  const float* bo = (const float*)d_in[9];
  float* out = (float*)d_out;
  char* ws = (char*)d_ws;

  unsigned short* hs_bf   = (unsigned short*)(ws);               // 16 MiB
  unsigned short* wall_bf = (unsigned short*)(ws + 16777216);    // 32 MiB [wq|wk|wv|wo]
  unsigned short* Qn      = (unsigned short*)(ws + 50331648);
  unsigned short* Kn      = (unsigned short*)(ws + 67108864);
  unsigned short* Vn      = (unsigned short*)(ws + 83886080);
  unsigned short* stT     = (unsigned short*)(ws + 100663296);
  unsigned short* cumT    = (unsigned short*)(ws + 117440512);
  unsigned short* aout    = (unsigned short*)(ws + 134217728);

  cvt_all<<<24576, 256, 0, stream>>>(hs, wq, wk, wv, wo, hs_bf, wall_bf);

  // fused QKV projection + feature map (8-phase half-recycled, counted vmcnt(4))
  gemm256_qkv<<<384, 512, 0, stream>>>(hs_bf, wall_bf, bq, bk, bv, Qn, Kn, Vn);

  chunk_state<<<dim3(32, 64), 256, 0, stream>>>(Kn, Vn, stT);
  prefix_state<<<1024, 256, 0, stream>>>(stT, cumT);
  attn_intra<<<dim3(32, 64), 256, 0, stream>>>(Qn, Kn, Vn, cumT, aout);

  gemm128_wo<<<256, 512, 0, stream>>>(aout, wall_bf + 12582912, bo, out);
}

// Round 11
// 197.346 us; speedup vs baseline: 1.1924x; 1.1924x over previous
//
#include <hip/hip_runtime.h>

typedef __bf16 bf16x8 __attribute__((ext_vector_type(8)));
typedef float f32x4 __attribute__((ext_vector_type(4)));

#define GLDS(g, l) __builtin_amdgcn_global_load_lds(                              \
    (const __attribute__((address_space(1))) void*)(g),                            \
    (__attribute__((address_space(3))) void*)(l), 16, 0, 0)

__device__ __forceinline__ unsigned short f2bf(float f) {
  unsigned int u = __builtin_bit_cast(unsigned int, f);
  u = (u + 0x7fffu + ((u >> 16) & 1u)) >> 16;
  return (unsigned short)u;
}
__device__ __forceinline__ float bf2f(unsigned short h) {
  unsigned int u = ((unsigned int)h) << 16;
  return __builtin_bit_cast(float, u);
}

// ---------------- merged convert: hs (2M float4) + 4 weights (1M float4 each) ----------------
__global__ __launch_bounds__(256) void cvt_all(
    const float* __restrict__ hs, const float* __restrict__ w0,
    const float* __restrict__ w1, const float* __restrict__ w2,
    const float* __restrict__ w3, unsigned short* __restrict__ hs_bf,
    unsigned short* __restrict__ wall_bf) {
  const int i = blockIdx.x * 256 + threadIdx.x;   // 0..6291455
  const float* src;
  unsigned short* dst;
  int off;
  if (i < 2097152) { src = hs; dst = hs_bf; off = i; }
  else {
    const int j = i - 2097152;
    const int y = j >> 20;                        // 0..3
    src = (y == 0) ? w0 : (y == 1) ? w1 : (y == 2) ? w2 : w3;
    dst = wall_bf + (size_t)y * 4194304;
    off = j & 1048575;
  }
  float4 v = ((const float4*)src)[off];
  ushort4 o;
  o.x = f2bf(v.x); o.y = f2bf(v.y); o.z = f2bf(v.z); o.w = f2bf(v.w);
  ((ushort4*)dst)[off] = o;
}

// ============ QKV GEMM (R4 config, best measured): BM=256 BN=384 BK=64, grid 256 exact ============
// 8 waves as 4M x 2N: wave tile 64 x 192 = 3 whole heads. acc[4][12].
// LDS: A 2x32KB + B 2x48KB = 160KB exact. Stages issued ph0-2, vmcnt(0) at tile end.
__global__ __launch_bounds__(512, 2) void gemm384_qkv(
    const unsigned short* __restrict__ A, const unsigned short* __restrict__ Bw,
    const float* __restrict__ bq, const float* __restrict__ bk, const float* __restrict__ bv,
    unsigned short* __restrict__ oQ, unsigned short* __restrict__ oK,
    unsigned short* __restrict__ oV) {
  constexpr int K = 2048, NT = 32;
  __shared__ unsigned short lds[81920];   // A: 2 x 16384 us @0, B: 2 x 24576 us @32768
  const int tid = threadIdx.x, lane = tid & 63, wid = tid >> 6;
  const int wm = wid >> 1, wn = wid & 1;

  // XCD bijective swizzle; 8 chunks of 4x8 tiles
  const int g0 = blockIdx.x;
  const int wg = (g0 & 7) * 32 + (g0 >> 3);
  const int chunk = wg >> 5, l = wg & 31;
  const int bx = (chunk & 3) * 4 + (l >> 3);   // 0..15 N-tiles (384 wide)
  const int by = (chunk >> 2) * 8 + (l & 7);   // 0..15 M-tiles (256 tall)

  const int rloc = tid >> 3;                              // 0..63 row within 64-row call
  const size_t gcoff = (size_t)(((lane & 7) ^ (lane >> 3)) << 3);
  const unsigned short* gA = A  + (size_t)(by * 256 + rloc) * K + gcoff;
  const unsigned short* gB = Bw + (size_t)(bx * 384 + rloc) * K + gcoff;

#define ABu(b) ((b) * 16384)
#define BBu(b) (32768 + (b) * 24576)
#define STAGE_A(c, b) GLDS(gA + (size_t)(c) * 64 * K, lds + ABu(b) + (c) * 4096 + wid * 512)
#define STAGE_B(c, b) GLDS(gB + (size_t)(c) * 64 * K, lds + BBu(b) + (c) * 4096 + wid * 512)

  // ds_read pieces (swizzled chunk = q ^ (row&7); 0-conflict measured)
  const int arow = (wm * 64 + (lane & 15)) * 64;    // + m*1024
  const int brow = (wn * 192 + (lane & 15)) * 64;   // + n*1024
  const int sw0 = (((lane >> 4)) ^ (lane & 7)) << 3;
  const int sw1 = ((4 + (lane >> 4)) ^ (lane & 7)) << 3;

  f32x4 acc[4][12] = {};

  // prologue: tile 0 -> buf 0
  STAGE_A(0, 0); STAGE_A(1, 0); STAGE_A(2, 0); STAGE_A(3, 0);
  STAGE_B(0, 0); STAGE_B(1, 0); STAGE_B(2, 0); STAGE_B(3, 0); STAGE_B(4, 0); STAGE_B(5, 0);
  gA += 64; gB += 64;
  asm volatile("s_waitcnt vmcnt(0)" ::: "memory");
  __builtin_amdgcn_s_barrier();

  for (int t = 0; t < NT; ++t) {
    const int Ab = ABu(t & 1) + arow;
    const int Bb = BBu(t & 1) + brow;
    const int sb = (t + 1) & 1;
    const bool st = (t + 1 < NT);
    bf16x8 Af[4], Bf[6];

    // ---- phase 0: kk0, n0-5 ----
    if (st) { STAGE_B(0, sb); STAGE_B(1, sb); STAGE_B(2, sb); }
#pragma unroll
    for (int m = 0; m < 4; ++m) Af[m] = *(const bf16x8*)&lds[Ab + m * 1024 + sw0];
#pragma unroll
    for (int n = 0; n < 6; ++n) Bf[n] = *(const bf16x8*)&lds[Bb + n * 1024 + sw0];
    __builtin_amdgcn_s_barrier();
    __builtin_amdgcn_s_setprio(1);
#pragma unroll
    for (int m = 0; m < 4; ++m)
#pragma unroll
      for (int n = 0; n < 6; ++n)
        acc[m][n] = __builtin_amdgcn_mfma_f32_16x16x32_bf16(Af[m], Bf[n], acc[m][n], 0, 0, 0);
    __builtin_amdgcn_s_setprio(0);
    __builtin_amdgcn_s_barrier();

    // ---- phase 1: kk0, n6-11 ----
    if (st) { STAGE_B(3, sb); STAGE_B(4, sb); STAGE_B(5, sb); }
#pragma unroll
    for (int n = 0; n < 6; ++n) Bf[n] = *(const bf16x8*)&lds[Bb + (n + 6) * 1024 + sw0];
    __builtin_amdgcn_s_barrier();
    __builtin_amdgcn_s_setprio(1);
#pragma unroll
    for (int m = 0; m < 4; ++m)
#pragma unroll
      for (int n = 0; n < 6; ++n)
        acc[m][n + 6] = __builtin_amdgcn_mfma_f32_16x16x32_bf16(Af[m], Bf[n], acc[m][n + 6], 0, 0, 0);
    __builtin_amdgcn_s_setprio(0);
    __builtin_amdgcn_s_barrier();

    // ---- phase 2: kk1, n0-5 ----
    if (st) { STAGE_A(0, sb); STAGE_A(1, sb); STAGE_A(2, sb); STAGE_A(3, sb); }
#pragma unroll
    for (int m = 0; m < 4; ++m) Af[m] = *(const bf16x8*)&lds[Ab + m * 1024 + sw1];
#pragma unroll
    for (int n = 0; n < 6; ++n) Bf[n] = *(const bf16x8*)&lds[Bb + n * 1024 + sw1];
    __builtin_amdgcn_s_barrier();
    __builtin_amdgcn_s_setprio(1);
#pragma unroll
    for (int m = 0; m < 4; ++m)
#pragma unroll
      for (int n = 0; n < 6; ++n)
        acc[m][n] = __builtin_amdgcn_mfma_f32_16x16x32_bf16(Af[m], Bf[n], acc[m][n], 0, 0, 0);
    __builtin_amdgcn_s_setprio(0);
    __builtin_amdgcn_s_barrier();

    // ---- phase 3: kk1, n6-11 ----
#pragma unroll
    for (int n = 0; n < 6; ++n) Bf[n] = *(const bf16x8*)&lds[Bb + (n + 6) * 1024 + sw1];
    __builtin_amdgcn_s_barrier();
    __builtin_amdgcn_s_setprio(1);
#pragma unroll
    for (int m = 0; m < 4; ++m)
#pragma unroll
      for (int n = 0; n < 6; ++n)
        acc[m][n + 6] = __builtin_amdgcn_mfma_f32_16x16x32_bf16(Af[m], Bf[n], acc[m][n + 6], 0, 0, 0);
    __builtin_amdgcn_s_setprio(0);
    if (st) {
      gA += 64; gB += 64;
      asm volatile("s_waitcnt vmcnt(0)" ::: "memory");
    }
    __builtin_amdgcn_s_barrier();
  }

  // ---------------- featmap epilogue: 3 whole heads per wave ----------------
  const int head0 = bx * 6 + wn * 3;
#pragma unroll
  for (int g = 0; g < 3; ++g) {
    const int head = head0 + g;       // uniform per wave
    const int type = head >> 5;       // 0 Q, 1 K, 2 V
    const int h = head & 31;
    const float* bias = (type == 0) ? bq : (type == 1) ? bk : bv;
    unsigned short* dst = (type == 0) ? oQ : (type == 1) ? oK : oV;
    float bv4[4];
#pragma unroll
    for (int j = 0; j < 4; ++j) bv4[j] = bias[h * 64 + j * 16 + (lane & 15)];
#pragma unroll
    for (int m = 0; m < 4; ++m) {
#pragma unroll
      for (int r = 0; r < 4; ++r) {
        const int row = by * 256 + wm * 64 + m * 16 + ((lane >> 4) << 2) + r;
        const int bb = row >> 11, s = row & 2047;
        float e[4];
        float loc = 0.f;
#pragma unroll
        for (int j = 0; j < 4; ++j) {
          float v = acc[m][g * 4 + j][r] + bv4[j];
          if (type == 0) v *= 0.125f;
          if (type < 2) v = (v > 0.f) ? (v + 1.f) : __expf(v);
          e[j] = v; loc += v;
        }
        if (type < 2) {
#pragma unroll
          for (int off = 1; off < 16; off <<= 1) loc += __shfl_xor(loc, off, 64);
          const float inv = 1.f / (loc + 1e-4f);
#pragma unroll
          for (int j = 0; j < 4; ++j) e[j] *= inv;
        }
        const size_t base = ((size_t)((bb << 5) + h) * 2048 + s) * 64;
#pragma unroll
        for (int j = 0; j < 4; ++j) dst[base + j * 16 + (lane & 15)] = f2bf(e[j]);
      }
    }
  }
#undef ABu
#undef BBu
#undef STAGE_A
#undef STAGE_B
}

// ---------------- wo GEMM (proven): BM=128 BN=256 BK=64, 3-buf, grid 256 ----------------
__global__ __launch_bounds__(512, 2) void gemm128_wo(
    const unsigned short* __restrict__ A, const unsigned short* __restrict__ Bw,
    const float* __restrict__ b0, float* __restrict__ C) {
  constexpr int K = 2048, NT = 32;
  __shared__ unsigned short lds[73728];
  const int tid = threadIdx.x, lane = tid & 63, wid = tid >> 6;
  const int wm = wid >> 2, wn = wid & 3;

  const int g0 = blockIdx.x;
  const int wg = (g0 & 7) * 32 + (g0 >> 3);
  const int l = wg % 32;
  const int chunk = wg / 32;
  const int bx2 = (chunk % 4) * 2 + l / 16;
  const int by2 = (chunk / 4) * 16 + l % 16;

  const int rloc = wid * 8 + (lane >> 3);
  const size_t gcoff = (size_t)(((lane & 7) ^ (lane >> 3)) << 3);
  const unsigned short* gA[2];
  const unsigned short* gB[4];
#pragma unroll
  for (int c = 0; c < 2; ++c) gA[c] = A + (size_t)(by2 * 128 + c * 64 + rloc) * K + gcoff;
#pragma unroll
  for (int c = 0; c < 4; ++c) gB[c] = Bw + (size_t)(bx2 * 256 + c * 64 + rloc) * K + gcoff;

  int aoff[4][2], boff[4][2];
#pragma unroll
  for (int m = 0; m < 4; ++m)
#pragma unroll
    for (int kk = 0; kk < 2; ++kk) {
      aoff[m][kk] = (wm * 64 + m * 16 + (lane & 15)) * 64 +
                    ((((kk << 2) + (lane >> 4)) ^ (lane & 7)) << 3);
      boff[m][kk] = (wn * 64 + m * 16 + (lane & 15)) * 64 +
                    ((((kk << 2) + (lane >> 4)) ^ (lane & 7)) << 3);
    }

  f32x4 acc[4][4] = {};

#define AB(b) ((b) * 8192)
#define BB(b) (24576 + (b) * 16384)
#define STAGE_A(c, b) GLDS(gA[c], lds + AB(b) + (c) * 4096 + wid * 512)
#define STAGE_B(c, b) GLDS(gB[c], lds + BB(b) + (c) * 4096 + wid * 512)

  STAGE_A(0, 0); STAGE_A(1, 0); STAGE_B(0, 0); STAGE_B(1, 0); STAGE_B(2, 0); STAGE_B(3, 0);
#pragma unroll
  for (int c = 0; c < 2; ++c) gA[c] += 64;
#pragma unroll
  for (int c = 0; c < 4; ++c) gB[c] += 64;
  STAGE_A(0, 1); STAGE_A(1, 1); STAGE_B(0, 1); STAGE_B(1, 1); STAGE_B(2, 1); STAGE_B(3, 1);
#pragma unroll
  for (int c = 0; c < 2; ++c) gA[c] += 64;
#pragma unroll
  for (int c = 0; c < 4; ++c) gB[c] += 64;
  asm volatile("s_waitcnt vmcnt(6)" ::: "memory");
  __builtin_amdgcn_s_barrier();

  for (int t = 0; t < NT; ++t) {
    const int b = t % 3;
    const int sb = (t + 2) % 3;
    const bool doStage = (t + 2 < NT);

    if (doStage) { STAGE_A(0, sb); STAGE_A(1, sb); STAGE_B(0, sb); STAGE_B(1, sb); }
    bf16x8 af[4], bfr[4];
#pragma unroll
    for (int m = 0; m < 4; ++m) af[m] = *(const bf16x8*)&lds[AB(b) + aoff[m][0]];
#pragma unroll
    for (int n = 0; n < 4; ++n) bfr[n] = *(const bf16x8*)&lds[BB(b) + boff[n][0]];
    __builtin_amdgcn_s_barrier();
    __builtin_amdgcn_s_setprio(1);
#pragma unroll
    for (int m = 0; m < 4; ++m)
#pragma unroll
      for (int n = 0; n < 4; ++n)
        acc[m][n] = __builtin_amdgcn_mfma_f32_16x16x32_bf16(af[m], bfr[n], acc[m][n], 0, 0, 0);
    __builtin_amdgcn_s_setprio(0);
    __builtin_amdgcn_s_barrier();

    if (doStage) { STAGE_B(2, sb); STAGE_B(3, sb); }
#pragma unroll
    for (int c = 0; c < 2; ++c) gA[c] += 64;
#pragma unroll
    for (int c = 0; c < 4; ++c) gB[c] += 64;
#pragma unroll
    for (int m = 0; m < 4; ++m) af[m] = *(const bf16x8*)&lds[AB(b) + aoff[m][1]];
#pragma unroll
    for (int n = 0; n < 4; ++n) bfr[n] = *(const bf16x8*)&lds[BB(b) + boff[n][1]];
    __builtin_amdgcn_s_barrier();
    __builtin_amdgcn_s_setprio(1);
#pragma unroll
    for (int m = 0; m < 4; ++m)
#pragma unroll
      for (int n = 0; n < 4; ++n)
        acc[m][n] = __builtin_amdgcn_mfma_f32_16x16x32_bf16(af[m], bfr[n], acc[m][n], 0, 0, 0);
    __builtin_amdgcn_s_setprio(0);
    if (t < NT - 1) {
      if (doStage) asm volatile("s_waitcnt vmcnt(6)" ::: "memory");
      else         asm volatile("s_waitcnt vmcnt(0)" ::: "memory");
    }
    __builtin_amdgcn_s_barrier();
  }

#pragma unroll
  for (int n = 0; n < 4; ++n) {
    const int col = bx2 * 256 + wn * 64 + n * 16 + (lane & 15);
    const float bv_ = b0[col];
#pragma unroll
    for (int m = 0; m < 4; ++m) {
      const int row0 = by2 * 128 + wm * 64 + m * 16 + ((lane >> 4) << 2);
#pragma unroll
      for (int r = 0; r < 4; ++r)
        C[(size_t)(row0 + r) * 2048 + col] = acc[m][n][r] + bv_;
    }
  }
#undef AB
#undef BB
#undef STAGE_A
#undef STAGE_B
}

// ---------------- pass1: per-chunk stateT[d][e] = sum_t v[t,d]*k[t,e] ----------------
__global__ __launch_bounds__(256) void chunk_state(
    const unsigned short* __restrict__ Kn, const unsigned short* __restrict__ Vn,
    unsigned short* __restrict__ stT) {
  __shared__ unsigned short Kt[64 * 72];
  __shared__ unsigned short Vt[64 * 72];
  const int c = blockIdx.x, bh = blockIdx.y;
  const int tid = threadIdx.x, lane = tid & 63, wid = tid >> 6;
  const size_t base = (size_t)bh * 2048 * 64 + (size_t)c * 64 * 64;
#pragma unroll
  for (int i = 0; i < 16; ++i) {
    const int ii = i * 256 + tid;
    const int t = ii >> 6, d = ii & 63;
    Kt[d * 72 + t] = Kn[base + ii];
    Vt[d * 72 + t] = Vn[base + ii];
  }
  __syncthreads();
  f32x4 acc[4] = {};
#pragma unroll
  for (int ks = 0; ks < 2; ++ks) {
    const int ko = ks * 32 + (lane >> 4) * 8;
    bf16x8 a = *(const bf16x8*)&Vt[(wid * 16 + (lane & 15)) * 72 + ko];
#pragma unroll
    for (int ej = 0; ej < 4; ++ej) {
      bf16x8 bb = *(const bf16x8*)&Kt[(ej * 16 + (lane & 15)) * 72 + ko];
      acc[ej] = __builtin_amdgcn_mfma_f32_16x16x32_bf16(a, bb, acc[ej], 0, 0, 0);
    }
  }
  const size_t obase = ((size_t)bh * 32 + c) * 4096;
#pragma unroll
  for (int ej = 0; ej < 4; ++ej) {
    const int e = ej * 16 + (lane & 15);
    const int d0 = wid * 16 + ((lane >> 4) << 2);
#pragma unroll
    for (int r = 0; r < 4; ++r)
      stT[obase + (size_t)(d0 + r) * 64 + e] = f2bf(acc[ej][r]);
  }
}

// ---------------- pass2: exclusive prefix over chunks ----------------
__global__ __launch_bounds__(256) void prefix_state(
    const unsigned short* __restrict__ stT, unsigned short* __restrict__ cumT) {
  const int g = blockIdx.x * 256 + threadIdx.x;
  const int bh = g >> 12, e = g & 4095;
  float run = 0.f;
  for (int c = 0; c < 32; ++c) {
    const size_t idx = (((size_t)bh * 32 + c) << 12) + e;
    const float v = bf2f(stT[idx]);
    cumT[idx] = f2bf(run);
    run += v;
  }
}

// ---------------- pass3: out = (tril(Q K^T) V + Q stateT) * 0.125 ----------------
__global__ __launch_bounds__(256) void attn_intra(
    const unsigned short* __restrict__ Qn, const unsigned short* __restrict__ Kn,
    const unsigned short* __restrict__ Vn, const unsigned short* __restrict__ cumT,
    unsigned short* __restrict__ aout) {
  __shared__ unsigned short Qs[64 * 72];
  __shared__ unsigned short Ks[64 * 72];
  __shared__ unsigned short Vt[64 * 72];
  __shared__ unsigned short St[64 * 72];
  __shared__ unsigned short Ps[64 * 72];
  const int c = blockIdx.x, bh = blockIdx.y;
  const int tid = threadIdx.x, lane = tid & 63, wid = tid >> 6;
  const size_t base = (size_t)bh * 2048 * 64 + (size_t)c * 64 * 64;
  const size_t sbase = ((size_t)bh * 32 + c) * 4096;
#pragma unroll
  for (int i = 0; i < 16; ++i) {
    const int ii = i * 256 + tid;
    const int t = ii >> 6, d = ii & 63;
    Qs[t * 72 + d] = Qn[base + ii];
    Ks[t * 72 + d] = Kn[base + ii];
    Vt[d * 72 + t] = Vn[base + ii];
    St[t * 72 + d] = cumT[sbase + ii];
  }
  __syncthreads();
  f32x4 sacc[4] = {};
#pragma unroll
  for (int ks = 0; ks < 2; ++ks) {
    const int ko = ks * 32 + (lane >> 4) * 8;
    bf16x8 a = *(const bf16x8*)&Qs[(wid * 16 + (lane & 15)) * 72 + ko];
#pragma unroll
    for (int tj = 0; tj < 4; ++tj) {
      bf16x8 bb = *(const bf16x8*)&Ks[(tj * 16 + (lane & 15)) * 72 + ko];
      sacc[tj] = __builtin_amdgcn_mfma_f32_16x16x32_bf16(a, bb, sacc[tj], 0, 0, 0);
    }
  }
#pragma unroll
  for (int tj = 0; tj < 4; ++tj) {
    const int t = tj * 16 + (lane & 15);
    const int s0 = wid * 16 + ((lane >> 4) << 2);
#pragma unroll
    for (int r = 0; r < 4; ++r) {
      const float v = (t <= s0 + r) ? sacc[tj][r] : 0.f;
      Ps[(s0 + r) * 72 + t] = f2bf(v);
    }
  }
  __syncthreads();
  f32x4 oacc[4] = {};
#pragma unroll
  for (int ks = 0; ks < 2; ++ks) {
    const int ko = ks * 32 + (lane >> 4) * 8;
    bf16x8 a = *(const bf16x8*)&Ps[(wid * 16 + (lane & 15)) * 72 + ko];
    bf16x8 a2 = *(const bf16x8*)&Qs[(wid * 16 + (lane & 15)) * 72 + ko];
#pragma unroll
    for (int dj = 0; dj < 4; ++dj) {
      bf16x8 bv_ = *(const bf16x8*)&Vt[(dj * 16 + (lane & 15)) * 72 + ko];
      oacc[dj] = __builtin_amdgcn_mfma_f32_16x16x32_bf16(a, bv_, oacc[dj], 0, 0, 0);
      bf16x8 bs_ = *(const bf16x8*)&St[(dj * 16 + (lane & 15)) * 72 + ko];
      oacc[dj] = __builtin_amdgcn_mfma_f32_16x16x32_bf16(a2, bs_, oacc[dj], 0, 0, 0);
    }
  }
  const int b = bh >> 5, h = bh & 31;
#pragma unroll
  for (int dj = 0; dj < 4; ++dj) {
    const int d = dj * 16 + (lane & 15);
    const int s0 = wid * 16 + ((lane >> 4) << 2);
#pragma unroll
    for (int r = 0; r < 4; ++r) {
      const size_t row = (size_t)(b * 2048 + c * 64 + s0 + r);
      aout[row * 2048 + h * 64 + d] = f2bf(0.125f * oacc[dj][r]);
    }
  }
}

extern "C" void kernel_launch(void* const* d_in, const int* in_sizes, int n_in,
                              void* d_out, int out_size, void* d_ws, size_t ws_size,
                              hipStream_t stream) {
  const float* hs = (const float*)d_in[0];
  const float* wq = (const float*)d_in[2];
  const float* bq = (const float*)d_in[3];
  const float* wk = (const float*)d_in[4];
  const float* bk = (const float*)d_in[5];
  const float* wv = (const float*)d_in[6];
  const float* bv = (const float*)d_in[7];
  const float* wo = (const float*)d_in[8];
  const float* bo = (const float*)d_in[9];
  float* out = (float*)d_out;
  char* ws = (char*)d_ws;

  unsigned short* hs_bf   = (unsigned short*)(ws);               // 16 MiB
  unsigned short* wall_bf = (unsigned short*)(ws + 16777216);    // 32 MiB [wq|wk|wv|wo]
  unsigned short* Qn      = (unsigned short*)(ws + 50331648);
  unsigned short* Kn      = (unsigned short*)(ws + 67108864);
  unsigned short* Vn      = (unsigned short*)(ws + 83886080);
  unsigned short* stT     = (unsigned short*)(ws + 100663296);
  unsigned short* cumT    = (unsigned short*)(ws + 117440512);
  unsigned short* aout    = (unsigned short*)(ws + 134217728);

  // merged convert (hs + all 4 weights) in one dispatch
  cvt_all<<<24576, 256, 0, stream>>>(hs, wq, wk, wv, wo, hs_bf, wall_bf);

  // fused QKV projection + feature map (R4/R9 best-measured config)
  gemm384_qkv<<<256, 512, 0, stream>>>(hs_bf, wall_bf, bq, bk, bv, Qn, Kn, Vn);

  chunk_state<<<dim3(32, 64), 256, 0, stream>>>(Kn, Vn, stT);
  prefix_state<<<1024, 256, 0, stream>>>(stT, cumT);
  attn_intra<<<dim3(32, 64), 256, 0, stream>>>(Qn, Kn, Vn, cumT, aout);

  gemm128_wo<<<256, 512, 0, stream>>>(aout, wall_bf + 12582912, bo, out);
}